// Round 7
// baseline (199.119 us; speedup 1.0000x reference)
//
#include <hip/hip_runtime.h>
#include <hip/hip_bf16.h>

using bf16 = __hip_bfloat16;
typedef __attribute__((ext_vector_type(8))) short short8x;            // 8 bf16 (4 VGPRs)
typedef __attribute__((ext_vector_type(4))) float f32x4;              // MFMA accumulator

__device__ __forceinline__ float b2f(bf16 x) { return __bfloat162float(x); }
__device__ __forceinline__ bf16  f2b(float x) { return __float2bfloat16(x); }
__device__ __forceinline__ short bbits(float x) { bf16 b = f2b(x); short s; __builtin_memcpy(&s, &b, 2); return s; }
__device__ __forceinline__ float bu2f(unsigned short s) {
    unsigned v = ((unsigned)s) << 16; float f; __builtin_memcpy(&f, &v, 4); return f;
}
// flag-dispatched input load: f32==1 -> fp32 storage, else bf16 storage
__device__ __forceinline__ float ldin(const void* p, int i, int f32) {
    return f32 ? ((const float*)p)[i] : b2f(((const bf16*)p)[i]);
}

// cheap exact-gelu: A&S 7.1.26 erf (abs err 1.5e-7), branchless
__device__ __forceinline__ float gelu_f(float x) {
    const float z = fabsf(x) * 0.70710678118654752f;
    const float t = __builtin_amdgcn_rcpf(1.0f + 0.3275911f * z);
    const float poly = t * (0.254829592f + t * (-0.284496736f +
                       t * (1.421413741f + t * (-1.453152027f + t * 1.061405429f))));
    const float erfv = 1.0f - poly * __expf(-z * z);
    return 0.5f * x * (1.0f + copysignf(erfv, x));
}

// problem dims (fixed by setup_inputs)
#define TI 6
#define HI 40
#define WI 40
#define TO 12
#define HO 80
#define WO 80
#define NIN (TI*HI*WI)    // 9600
#define NOUT (TO*HO*WO)   // 76800

// ---------------- workspace layout ----------------
// [0)            : featT bf16 [NIN][64]
// [+FEATT_BYTES) : fc1P bf16 [8 kc][16 nt][64 lane][8]   (fc1 B-fragments, K=256)
// [+FC1P_BYTES)  : W1fP bf16 [16 kc][16 nt][64 lane][8]  (W1f B-fragments, K=512)
// float region F (offsets in floats):
#define F_B1    0                       // [256] effective bias (pw1_b + pw1·dw1_b + rel_cell)
#define F_ACO   (F_B1 + 256)            // [6][256] rel-coord coefficients
#define F_SC    (F_ACO + 6*256)         // [3][NIN] shortcut conv output
#define F_DT    (F_SC + 3*NIN)          // [2][TO] signed d (t axis)
#define F_DH    (F_DT + 2*TO)           // [2][HO]
#define F_DW    (F_DH + 2*HO)           // [2][WO]
#define F_FT    (F_DW + 2*WO)           // [TO] trilinear frac
#define F_FH    (F_FT + TO)             // [HO]
#define F_FW    (F_FH + HO)             // [WO]
#define F_FC1B  (F_FW + WO)             // [256] fc1 bias
#define F_FC2W  (F_FC1B + 256)          // [3*256] fc2 weights
#define F_FC2B  (F_FC2W + 768)          // [3] fc2 bias (pad 4)
#define F_END   (F_FC2B + 4)
// int region I:
#define I_IT    0
#define I_IH    (I_IT + 2*TO)
#define I_IW    (I_IH + 2*HO)
#define I_LT0   (I_IW + 2*WO)
#define I_LT1   (I_LT0 + TO)
#define I_LH0   (I_LT1 + TO)
#define I_LH1   (I_LH0 + HO)
#define I_LW0   (I_LH1 + HO)
#define I_LW1   (I_LW0 + WO)
#define I_FLAG  (I_LW1 + WO)
#define I_END   (I_FLAG + 1)

#define MPOS 32     // positions per k_main block
#define USTR 552    // u row stride in shorts: 8 corners * (64+4 pad) + 8  (2-way-max banks)
#define CSTR 68     // per-corner stride in u
#define ZPAD 264    // z row stride in shorts

// per-axis tables, replicating reference `near` (eps=1e-6, round-half-even) and `lin_idx`
__device__ __forceinline__ void axis_tables(int i, int n_out, int n_in,
                                            float* dvals, int* ivals,
                                            int* l0, int* l1, float* fr) {
    const float r_out = 1.0f / (float)n_out;
    const float r_in  = 1.0f / (float)n_in;
    const float c = -1.0f + r_out + 2.0f * r_out * (float)i;
    #pragma unroll
    for (int v = 0; v < 2; ++v) {
        const float vv = v ? 1.0f : -1.0f;
        float cc = c + vv * r_in + 1e-6f;
        cc = fminf(fmaxf(cc, -1.0f + 1e-6f), 1.0f - 1e-6f);
        float fx = rintf(((cc + 1.0f) * (float)n_in - 1.0f) * 0.5f);
        fx = fminf(fmaxf(fx, 0.0f), (float)(n_in - 1));
        const int idx = (int)fx;
        const float l = -1.0f + r_in + 2.0f * r_in * (float)idx;
        dvals[v * n_out + i] = (c - l) * (float)n_in;
        ivals[v * n_out + i] = idx;
    }
    float x = fminf(fmaxf(((c + 1.0f) * (float)n_in - 1.0f) * 0.5f, 0.0f), (float)(n_in - 1));
    const float x0 = floorf(x);
    fr[i] = x - x0;
    const int i0 = (int)x0;
    l0[i] = i0;
    l1[i] = min(i0 + 1, n_in - 1);
}

// ---------------- kernel A: merged setup (183 blocks) ----------------
// blocks 0..15  : W1f fold (B1/ACO) + W1fP pack, nt = b
// blocks 16..31 : fc1P pack, nt = b-16
// blocks 32..181: featT transpose + shortcut sc, tile = b-32 (64 positions)
// block  182    : dtype flag + axis tables + fc1_b/fc2 staging
__global__ __launch_bounds__(256)
void k_setup(const void* __restrict__ feat,
             const void* __restrict__ dw1_w, const void* __restrict__ dw1_b,
             const void* __restrict__ pw1_w, const void* __restrict__ pw1_b,
             const void* __restrict__ fc1_w, const void* __restrict__ fc1_b,
             const void* __restrict__ fc2_w, const void* __restrict__ fc2_b,
             const void* __restrict__ sc_dw_w, const void* __restrict__ sc_dw_b,
             const void* __restrict__ sc_pw_w, const void* __restrict__ sc_pw_b,
             bf16* __restrict__ featT, bf16* __restrict__ fc1P,
             bf16* __restrict__ W1fP, float* __restrict__ F, int* __restrict__ I) {
    const int tid = threadIdx.x;
    const int b = blockIdx.x;
    __shared__ int sflag;
    // per-block dtype detection (wave-0 ballot): even halfwords of fp32 data
    // are mantissa junk (~15% in bf16-exponent window); of bf16 data ~100%.
    if (tid < 64) {
        const unsigned short* u = (const unsigned short*)feat;
        const unsigned e = (u[2 * tid] >> 7) & 0xFFu;
        const unsigned long long m = __ballot(e >= 0x68u && e <= 0x8Eu);
        if (tid == 0) sflag = (__popcll(m) < 32) ? 1 : 0;
    }
    __syncthreads();
    const int f32 = sflag;

    if (b < 16) {
        // ---- W1f fold + pack; rows n = b*16 + r ----
        const int nt = b;
        __shared__ float rowb[16][540];
        __shared__ float dwl[544];
        __shared__ float dbl[544];
        for (int ch = tid; ch < 539; ch += 256) {
            dwl[ch] = ldin(dw1_w, ch, f32);
            dbl[ch] = ldin(dw1_b, ch, f32);
        }
        for (int r = 0; r < 16; ++r)
            for (int ch = tid; ch < 539; ch += 256)
                rowb[r][ch] = ldin(pw1_w, (nt * 16 + r) * 539 + ch, f32);
        __syncthreads();

        // B1 + ACO: 16 lanes per row
        {
            const int r = tid >> 4, part = tid & 15;
            float s = 0.f;
            for (int ch = part; ch < 539; ch += 16) s += rowb[r][ch] * dbl[ch];
            #pragma unroll
            for (int m = 1; m <= 8; m <<= 1) s += __shfl_xor(s, m, 64);
            if (part == 0) {
                const int n = nt * 16 + r;
                float bacc = ldin(pw1_b, n, f32) + s;
                #pragma unroll
                for (int ch = 536; ch < 539; ++ch) bacc += 2.0f * rowb[r][ch] * dwl[ch];
                F[F_B1 + n] = bacc;
                float A[6] = {0.f, 0.f, 0.f, 0.f, 0.f, 0.f};
                #pragma unroll
                for (int k = 0; k < 8; ++k) {
                    A[(k >> 2)]           += rowb[r][3*k + 0] * dwl[3*k + 0];
                    A[2 + ((k >> 1) & 1)] += rowb[r][3*k + 1] * dwl[3*k + 1];
                    A[4 + (k & 1)]        += rowb[r][3*k + 2] * dwl[3*k + 2];
                }
                #pragma unroll
                for (int i = 0; i < 6; ++i) F[F_ACO + i * 256 + n] = A[i];
            }
        }
        // W1fP pack: K = kc*32 + (wl>>4)*8 + jj, channel = 24 + K
        for (int it = 0; it < 4; ++it) {
            const int gl = it * 256 + tid;          // 0..1023
            const int kc = gl >> 6, wl = gl & 63;
            const int nl = wl & 15;
            const int K0 = kc * 32 + (wl >> 4) * 8;
            bf16 v[8];
            #pragma unroll
            for (int jj = 0; jj < 8; ++jj)
                v[jj] = f2b(rowb[nl][24 + K0 + jj] * dwl[24 + K0 + jj]);
            *(short8x*)&W1fP[((size_t)(kc * 16 + nt) * 64 + wl) * 8] = *(short8x*)v;
        }
        return;
    }
    if (b < 32) {
        // ---- fc1P pack; rows n = (b-16)*16 + r ----
        const int nt = b - 16;
        __shared__ float rowf[16][260];
        for (int r = 0; r < 16; ++r)
            rowf[r][tid] = ldin(fc1_w, (nt * 16 + r) * 256 + tid, f32);
        __syncthreads();
        for (int it = 0; it < 2; ++it) {
            const int gl = it * 256 + tid;          // 0..511
            const int kc = gl >> 6, wl = gl & 63;
            const int nl = wl & 15;
            const int K0 = kc * 32 + (wl >> 4) * 8;
            bf16 v[8];
            #pragma unroll
            for (int jj = 0; jj < 8; ++jj) v[jj] = f2b(rowf[nl][K0 + jj]);
            *(short8x*)&fc1P[((size_t)(kc * 16 + nt) * 64 + wl) * 8] = *(short8x*)v;
        }
        return;
    }
    if (b < 182) {
        // ---- featT transpose + shortcut; 64 positions ----
        const int pos0 = (b - 32) * 64;
        __shared__ float tF[64][66];
        __shared__ float scw_l[3][64];
        __shared__ float scb_l[4];
        {
            const int p = tid & 63, cg = tid >> 6;
            #pragma unroll
            for (int cc = 0; cc < 16; ++cc) {
                const int c = cg * 16 + cc;
                tF[c][p] = ldin(feat, c * NIN + pos0 + p, f32);
            }
        }
        if (tid < 192)
            scw_l[tid >> 6][tid & 63] = ldin(sc_pw_w, tid, f32) * ldin(sc_dw_w, tid & 63, f32);
        if (tid < 3) {
            float sb = ldin(sc_pw_b, tid, f32);
            for (int c = 0; c < 64; ++c)
                sb += ldin(sc_pw_w, tid * 64 + c, f32) * ldin(sc_dw_b, c, f32);
            scb_l[tid] = sb;
        }
        __syncthreads();
        for (int it = 0; it < 2; ++it) {
            const int id = it * 256 + tid;          // 0..511
            const int p = id >> 3, c8 = id & 7;
            bf16 v[8];
            #pragma unroll
            for (int jj = 0; jj < 8; ++jj) v[jj] = f2b(tF[c8 * 8 + jj][p]);
            *(short8x*)&featT[(size_t)(pos0 + p) * 64 + c8 * 8] = *(short8x*)v;
        }
        if (tid < 192) {
            const int j = tid >> 6, p = tid & 63;
            float s = scb_l[j];
            for (int c = 0; c < 64; ++c) s += tF[c][p] * scw_l[j][c];
            F[F_SC + j * NIN + pos0 + p] = s;
        }
        return;
    }
    // ---- block 182: flag + tables + small staging ----
    if (tid == 0) I[I_FLAG] = f32;
    F[F_FC1B + tid] = ldin(fc1_b, tid, f32);
    for (int r = tid; r < 768; r += 256) F[F_FC2W + r] = ldin(fc2_w, r, f32);
    if (tid < 3) F[F_FC2B + tid] = ldin(fc2_b, tid, f32);
    if (tid < TO) axis_tables(tid, TO, TI, F + F_DT, I + I_IT, I + I_LT0, I + I_LT1, F + F_FT);
    if (tid < HO) axis_tables(tid, HO, HI, F + F_DH, I + I_IH, I + I_LH0, I + I_LH1, F + F_FH);
    if (tid < WO) axis_tables(tid, WO, WI, F + F_DW, I + I_IW, I + I_LW0, I + I_LW1, F + F_FW);
}

// ---------------- kernel B: fully fused main (z-GEMM K=512 -> fc1 -> gelu -> fc2) ----------------
__global__ __launch_bounds__(256, 4)
void k_main(const bf16* __restrict__ featT, const bf16* __restrict__ fc1P,
            const bf16* __restrict__ W1fP, const float* __restrict__ F,
            const int* __restrict__ I, void* __restrict__ outv) {
    const int tid = threadIdx.x;
    const int pos0 = blockIdx.x * MPOS;
    const int f32 = I[I_FLAG];

    __shared__ __align__(16) short ubuf[MPOS * USTR];  // u[p][corner][c]; aliased as z[p][o] later
    __shared__ float redc[MPOS * 4 * 3];
    __shared__ int   sh_ipos[MPOS][8];
    __shared__ float sh_wk[MPOS][8];
    __shared__ float sh_dv[MPOS][6];
    __shared__ float sh_g[3][MPOS];

    // ---- stage 1: per-position scalars (threads 0..31) ----
    if (tid < MPOS) {
        const int p = tid;
        const int pos = pos0 + p;
        const int t = pos / (HO * WO);
        const int rem = pos - t * (HO * WO);
        const int h = rem / WO;
        const int w = rem - h * WO;
        const int   iTa[2] = { I[I_IT + t], I[I_IT + TO + t] };
        const float dTv[2] = { F[F_DT + t], F[F_DT + TO + t] };
        const int   iHa[2] = { I[I_IH + h], I[I_IH + HO + h] };
        const float dHv[2] = { F[F_DH + h], F[F_DH + HO + h] };
        const int   iWa[2] = { I[I_IW + w], I[I_IW + WO + w] };
        const float dWv[2] = { F[F_DW + w], F[F_DW + WO + w] };
        sh_dv[p][0] = dTv[0]; sh_dv[p][1] = dTv[1];
        sh_dv[p][2] = dHv[0]; sh_dv[p][3] = dHv[1];
        sh_dv[p][4] = dWv[0]; sh_dv[p][5] = dWv[1];
        const float aT[2] = { fabsf(dTv[0]), fabsf(dTv[1]) };
        const float aH[2] = { fabsf(dHv[0]), fabsf(dHv[1]) };
        const float aW[2] = { fabsf(dWv[0]), fabsf(dWv[1]) };
        const float tot = (aT[0] + aT[1]) * (aH[0] + aH[1]) * (aW[0] + aW[1]) + 8e-9f;
        #pragma unroll
        for (int k = 0; k < 8; ++k) {
            const int at = k >> 2, ah = (k >> 1) & 1, aw = k & 1;
            sh_wk[p][k] = (aT[1 - at] * aH[1 - ah] * aW[1 - aw] + 1e-9f) / tot;
            sh_ipos[p][k] = iTa[at] * (HI * WI) + iHa[ah] * WI + iWa[aw];
        }
        // trilinear shortcut g
        const int a0 = I[I_LT0 + t], a1 = I[I_LT1 + t];
        const int bh0 = I[I_LH0 + h], bh1 = I[I_LH1 + h];
        const int c0 = I[I_LW0 + w], c1 = I[I_LW1 + w];
        const float fT = F[F_FT + t], fH = F[F_FH + h], fW = F[F_FW + w];
        #pragma unroll
        for (int jj = 0; jj < 3; ++jj) {
            const float* Sj = F + F_SC + jj * NIN;
            const int i0 = a0 * (HI * WI), i1 = a1 * (HI * WI);
            const float v000 = Sj[i0 + bh0 * WI + c0], v001 = Sj[i0 + bh0 * WI + c1];
            const float v010 = Sj[i0 + bh1 * WI + c0], v011 = Sj[i0 + bh1 * WI + c1];
            const float v100 = Sj[i1 + bh0 * WI + c0], v101 = Sj[i1 + bh0 * WI + c1];
            const float v110 = Sj[i1 + bh1 * WI + c0], v111 = Sj[i1 + bh1 * WI + c1];
            const float u00 = v000 * (1.f - fT) + v100 * fT;
            const float u01 = v001 * (1.f - fT) + v101 * fT;
            const float u10 = v010 * (1.f - fT) + v110 * fT;
            const float u11 = v011 * (1.f - fT) + v111 * fT;
            const float q0 = u00 * (1.f - fH) + u10 * fH;
            const float q1 = u01 * (1.f - fH) + u11 * fH;
            sh_g[jj][p] = q0 * (1.f - fW) + q1 * fW;
        }
    }
    __syncthreads();

    // ---- stage 2: build u[p][k][c] = wk * featT[ipos[p][k]][c]  (bf16) ----
    {
        const int c8 = tid & 7;
        int pair = tid >> 3;                 // (p,k) pair index, +32 per iter
        #pragma unroll
        for (int it = 0; it < 8; ++it, pair += 32) {
            const int p = pair >> 3, k = pair & 7;
            const int row = sh_ipos[p][k];
            const float wk = sh_wk[p][k];
            const short8x fr = *(const short8x*)(featT + (size_t)row * 64 + c8 * 8);
            short v[8];
            #pragma unroll
            for (int jj = 0; jj < 8; ++jj)
                v[jj] = bbits(wk * bu2f((unsigned short)fr[jj]));
            *(short8x*)&ubuf[p * USTR + k * CSTR + c8 * 8] = *(short8x*)v;
        }
    }
    __syncthreads();

    // ---- stage 3: z-GEMM (M=32,N=256,K=512) + bias/ACO epilogue -> z bf16 in ubuf ----
    const int wl = tid & 63, w = tid >> 6;
    const int col = wl & 15, quad = wl >> 4;
    {
        f32x4 zacc[2][4] = { { {0,0,0,0},{0,0,0,0},{0,0,0,0},{0,0,0,0} },
                             { {0,0,0,0},{0,0,0,0},{0,0,0,0},{0,0,0,0} } };
        const short8x* bp = (const short8x*)W1fP;
        #pragma unroll
        for (int kc = 0; kc < 16; ++kc) {
            const int corner = kc >> 1;
            const int cin = (kc & 1) * 32 + quad * 8;
            const short8x a0 = *(const short8x*)&ubuf[col * USTR + corner * CSTR + cin];
            const short8x a1 = *(const short8x*)&ubuf[(col + 16) * USTR + corner * CSTR + cin];
            #pragma unroll
            for (int nt = 0; nt < 4; ++nt) {
                const short8x bb = bp[((size_t)kc * 16 + w * 4 + nt) * 64 + wl];
                zacc[0][nt] = __builtin_amdgcn_mfma_f32_16x16x32_bf16(a0, bb, zacc[0][nt], 0, 0, 0);
                zacc[1][nt] = __builtin_amdgcn_mfma_f32_16x16x32_bf16(a1, bb, zacc[1][nt], 0, 0, 0);
            }
        }
        __syncthreads();   // all u reads complete before aliasing ubuf as z
        // epilogue: z = zacc + b1 + Acoef·dv; D layout m=quad*4+r (+16 mt), n=w*64+nt*16+col
        #pragma unroll
        for (int nt = 0; nt < 4; ++nt) {
            const int n = w * 64 + nt * 16 + col;
            const float b1 = F[F_B1 + n];
            float Ac[6];
            #pragma unroll
            for (int i = 0; i < 6; ++i) Ac[i] = F[F_ACO + i * 256 + n];
            #pragma unroll
            for (int mt = 0; mt < 2; ++mt)
                #pragma unroll
                for (int r = 0; r < 4; ++r) {
                    const int p = mt * 16 + quad * 4 + r;
                    float x = zacc[mt][nt][r] + b1;
                    #pragma unroll
                    for (int i = 0; i < 6; ++i) x += Ac[i] * sh_dv[p][i];
                    ubuf[p * ZPAD + n] = bbits(x);
                }
        }
    }
    __syncthreads();

    // ---- stage 4: fc1 via MFMA + gelu + fc2 partials in-register ----
    {
        f32x4 acc0[4] = { {0,0,0,0}, {0,0,0,0}, {0,0,0,0}, {0,0,0,0} };
        f32x4 acc1[4] = { {0,0,0,0}, {0,0,0,0}, {0,0,0,0}, {0,0,0,0} };
        const short8x* bp = (const short8x*)fc1P;
        #pragma unroll
        for (int kc = 0; kc < 8; ++kc) {
            const short8x a0 = *(const short8x*)&ubuf[col * ZPAD + kc * 32 + quad * 8];
            const short8x a1 = *(const short8x*)&ubuf[(col + 16) * ZPAD + kc * 32 + quad * 8];
            #pragma unroll
            for (int nt = 0; nt < 4; ++nt) {
                const short8x b = bp[((size_t)kc * 16 + w * 4 + nt) * 64 + wl];
                acc0[nt] = __builtin_amdgcn_mfma_f32_16x16x32_bf16(a0, b, acc0[nt], 0, 0, 0);
                acc1[nt] = __builtin_amdgcn_mfma_f32_16x16x32_bf16(a1, b, acc1[nt], 0, 0, 0);
            }
        }
        float part[2][3][4];
        #pragma unroll
        for (int mt = 0; mt < 2; ++mt)
            #pragma unroll
            for (int jj = 0; jj < 3; ++jj)
                #pragma unroll
                for (int r = 0; r < 4; ++r) part[mt][jj][r] = 0.f;
        #pragma unroll
        for (int nt = 0; nt < 4; ++nt) {
            const int j = w * 64 + nt * 16 + col;
            const float fb = F[F_FC1B + j];
            const float w0 = F[F_FC2W + j];
            const float w1 = F[F_FC2W + 256 + j];
            const float w2 = F[F_FC2W + 512 + j];
            #pragma unroll
            for (int r = 0; r < 4; ++r) {
                float hh = gelu_f(acc0[nt][r] + fb);
                part[0][0][r] += w0 * hh; part[0][1][r] += w1 * hh; part[0][2][r] += w2 * hh;
                hh = gelu_f(acc1[nt][r] + fb);
                part[1][0][r] += w0 * hh; part[1][1][r] += w1 * hh; part[1][2][r] += w2 * hh;
            }
        }
        // butterfly-reduce over the 16 col-lanes
        #pragma unroll
        for (int m = 1; m <= 8; m <<= 1)
            #pragma unroll
            for (int mt = 0; mt < 2; ++mt)
                #pragma unroll
                for (int jj = 0; jj < 3; ++jj)
                    #pragma unroll
                    for (int r = 0; r < 4; ++r)
                        part[mt][jj][r] += __shfl_xor(part[mt][jj][r], m, 64);
        if (col == 0) {
            #pragma unroll
            for (int mt = 0; mt < 2; ++mt)
                #pragma unroll
                for (int jj = 0; jj < 3; ++jj)
                    #pragma unroll
                    for (int r = 0; r < 4; ++r) {
                        const int p = mt * 16 + quad * 4 + r;
                        redc[(p * 4 + w) * 3 + jj] = part[mt][jj][r];
                    }
        }
    }
    __syncthreads();

    // ---- stage 5: combine 4 wave-partials + shortcut + store ----
    if (tid < 96) {
        const int p = tid / 3, jj = tid - 3 * p;
        float a = F[F_FC2B + jj] + sh_g[jj][p];
        #pragma unroll
        for (int w2 = 0; w2 < 4; ++w2) a += redc[(p * 4 + w2) * 3 + jj];
        const int oidx = jj * NOUT + pos0 + p;
        if (f32) ((float*)outv)[oidx] = a;
        else     ((bf16*)outv)[oidx] = f2b(a);
    }
}

extern "C" void kernel_launch(void* const* d_in, const int* in_sizes, int n_in,
                              void* d_out, int out_size, void* d_ws, size_t ws_size,
                              hipStream_t stream) {
    const void* feat    = d_in[0];
    const void* dw1_w   = d_in[1];
    const void* dw1_b   = d_in[2];
    const void* pw1_w   = d_in[3];
    const void* pw1_b   = d_in[4];
    const void* fc1_w   = d_in[5];
    const void* fc1_b   = d_in[6];
    const void* fc2_w   = d_in[7];
    const void* fc2_b   = d_in[8];
    const void* sc_dw_w = d_in[9];
    const void* sc_dw_b = d_in[10];
    const void* sc_pw_w = d_in[11];
    const void* sc_pw_b = d_in[12];

    const size_t FEATT_BYTES = (size_t)NIN * 64 * 2;      // 1,228,800
    const size_t FC1P_BYTES  = (size_t)256 * 256 * 2;     // 131,072
    const size_t W1FP_BYTES  = (size_t)512 * 256 * 2;     // 262,144
    bf16*  featT = (bf16*)d_ws;
    bf16*  fc1P  = (bf16*)((char*)d_ws + FEATT_BYTES);
    bf16*  W1fP  = (bf16*)((char*)d_ws + FEATT_BYTES + FC1P_BYTES);
    float* F     = (float*)((char*)d_ws + FEATT_BYTES + FC1P_BYTES + W1FP_BYTES);
    int*   I     = (int*)(F + F_END);
    // total ws need ~1.8 MB

    k_setup<<<183, 256, 0, stream>>>(feat, dw1_w, dw1_b, pw1_w, pw1_b, fc1_w, fc1_b,
                                     fc2_w, fc2_b, sc_dw_w, sc_dw_b, sc_pw_w, sc_pw_b,
                                     featT, fc1P, W1fP, F, I);
    k_main<<<NOUT / MPOS, 256, 0, stream>>>(featT, fc1P, W1fP, F, I, (void*)d_out);
}

// Round 8
// 180.727 us; speedup vs baseline: 1.1018x; 1.1018x over previous
//
#include <hip/hip_runtime.h>
#include <hip/hip_bf16.h>

using bf16 = __hip_bfloat16;
typedef __attribute__((ext_vector_type(8))) short short8x;            // 8 bf16 (4 VGPRs)
typedef __attribute__((ext_vector_type(4))) float f32x4;              // MFMA accumulator

__device__ __forceinline__ float b2f(bf16 x) { return __bfloat162float(x); }
__device__ __forceinline__ bf16  f2b(float x) { return __float2bfloat16(x); }
__device__ __forceinline__ short bbits(float x) { bf16 b = f2b(x); short s; __builtin_memcpy(&s, &b, 2); return s; }
__device__ __forceinline__ float bu2f(unsigned short s) {
    unsigned v = ((unsigned)s) << 16; float f; __builtin_memcpy(&f, &v, 4); return f;
}
// flag-dispatched input load: f32==1 -> fp32 storage, else bf16 storage
__device__ __forceinline__ float ldin(const void* p, int i, int f32) {
    return f32 ? ((const float*)p)[i] : b2f(((const bf16*)p)[i]);
}

// cheap exact-gelu: A&S 7.1.26 erf (abs err 1.5e-7), branchless
__device__ __forceinline__ float gelu_f(float x) {
    const float z = fabsf(x) * 0.70710678118654752f;
    const float t = __builtin_amdgcn_rcpf(1.0f + 0.3275911f * z);
    const float poly = t * (0.254829592f + t * (-0.284496736f +
                       t * (1.421413741f + t * (-1.453152027f + t * 1.061405429f))));
    const float erfv = 1.0f - poly * __expf(-z * z);
    return 0.5f * x * (1.0f + copysignf(erfv, x));
}

// problem dims (fixed by setup_inputs)
#define TI 6
#define HI 40
#define WI 40
#define TO 12
#define HO 80
#define WO 80
#define NIN (TI*HI*WI)    // 9600
#define NOUT (TO*HO*WO)   // 76800

// ---------------- workspace layout ----------------
// [0)            : featT bf16 [NIN][64]
// [+FEATT_BYTES) : fc1P bf16 [8 kc][16 nt][64 lane][8]   (fc1 B-fragments, K=256)
// [+FC1P_BYTES)  : W1fP bf16 [16 kc][16 nt][64 lane][8]  (W1f B-fragments, K=512)
// float region F (offsets in floats):
#define F_B1    0                       // [256] effective bias (pw1_b + pw1·dw1_b + rel_cell)
#define F_ACO   (F_B1 + 256)            // [6][256] rel-coord coefficients
#define F_SC    (F_ACO + 6*256)         // [3][NIN] shortcut conv output
#define F_DT    (F_SC + 3*NIN)          // [2][TO] signed d (t axis)
#define F_DH    (F_DT + 2*TO)           // [2][HO]
#define F_DW    (F_DH + 2*HO)           // [2][WO]
#define F_FT    (F_DW + 2*WO)           // [TO] trilinear frac
#define F_FH    (F_FT + TO)             // [HO]
#define F_FW    (F_FH + HO)             // [WO]
#define F_FC1B  (F_FW + WO)             // [256] fc1 bias
#define F_FC2W  (F_FC1B + 256)          // [3*256] fc2 weights
#define F_FC2B  (F_FC2W + 768)          // [3] fc2 bias (pad 4)
#define F_END   (F_FC2B + 4)
// int region I:
#define I_IT    0
#define I_IH    (I_IT + 2*TO)
#define I_IW    (I_IH + 2*HO)
#define I_LT0   (I_IW + 2*WO)
#define I_LT1   (I_LT0 + TO)
#define I_LH0   (I_LT1 + TO)
#define I_LH1   (I_LH0 + HO)
#define I_LW0   (I_LH1 + HO)
#define I_LW1   (I_LW0 + WO)
#define I_FLAG  (I_LW1 + WO)
#define I_END   (I_FLAG + 1)

#define MPOS 32     // positions per k_main block
#define CSTR 72     // per-corner stride in u (shorts): 144 B, 16B-aligned
#define USTR (8*CSTR)  // 576 shorts per position row (1152 B, 16B-aligned)
#define ZPAD 264    // z row stride in shorts (528 B, 16B-aligned)

// per-axis tables, replicating reference `near` (eps=1e-6, round-half-even) and `lin_idx`
__device__ __forceinline__ void axis_tables(int i, int n_out, int n_in,
                                            float* dvals, int* ivals,
                                            int* l0, int* l1, float* fr) {
    const float r_out = 1.0f / (float)n_out;
    const float r_in  = 1.0f / (float)n_in;
    const float c = -1.0f + r_out + 2.0f * r_out * (float)i;
    #pragma unroll
    for (int v = 0; v < 2; ++v) {
        const float vv = v ? 1.0f : -1.0f;
        float cc = c + vv * r_in + 1e-6f;
        cc = fminf(fmaxf(cc, -1.0f + 1e-6f), 1.0f - 1e-6f);
        float fx = rintf(((cc + 1.0f) * (float)n_in - 1.0f) * 0.5f);
        fx = fminf(fmaxf(fx, 0.0f), (float)(n_in - 1));
        const int idx = (int)fx;
        const float l = -1.0f + r_in + 2.0f * r_in * (float)idx;
        dvals[v * n_out + i] = (c - l) * (float)n_in;
        ivals[v * n_out + i] = idx;
    }
    float x = fminf(fmaxf(((c + 1.0f) * (float)n_in - 1.0f) * 0.5f, 0.0f), (float)(n_in - 1));
    const float x0 = floorf(x);
    fr[i] = x - x0;
    const int i0 = (int)x0;
    l0[i] = i0;
    l1[i] = min(i0 + 1, n_in - 1);
}

// ---------------- kernel A: flat setup (263 blocks, shallow coalesced duties) ----------------
// b in [0,150)   : featT transpose + shortcut sc (64 positions per block)
// b in [150,214) : W1fP pack (one B-fragment per thread, direct from global)
// b in [214,246) : fc1P pack (one B-fragment per thread)
// b in [246,262) : B1 + ACO fold (16 channels per block, 16-lane strided reduce)
// b == 262       : dtype flag + axis tables + fc1_b/fc2 staging
__global__ __launch_bounds__(256)
void k_setup(const void* __restrict__ feat,
             const void* __restrict__ dw1_w, const void* __restrict__ dw1_b,
             const void* __restrict__ pw1_w, const void* __restrict__ pw1_b,
             const void* __restrict__ fc1_w, const void* __restrict__ fc1_b,
             const void* __restrict__ fc2_w, const void* __restrict__ fc2_b,
             const void* __restrict__ sc_dw_w, const void* __restrict__ sc_dw_b,
             const void* __restrict__ sc_pw_w, const void* __restrict__ sc_pw_b,
             bf16* __restrict__ featT, bf16* __restrict__ fc1P,
             bf16* __restrict__ W1fP, float* __restrict__ F, int* __restrict__ I) {
    const int tid = threadIdx.x;
    const int b = blockIdx.x;
    __shared__ int sflag;
    // per-block dtype detection (wave-0 ballot): even halfwords of fp32 data
    // are mantissa junk (~15% in bf16-exponent window); of bf16 data ~100%.
    if (tid < 64) {
        const unsigned short* u = (const unsigned short*)feat;
        const unsigned e = (u[2 * tid] >> 7) & 0xFFu;
        const unsigned long long m = __ballot(e >= 0x68u && e <= 0x8Eu);
        if (tid == 0) sflag = (__popcll(m) < 32) ? 1 : 0;
    }
    __syncthreads();
    const int f32 = sflag;

    if (b < 150) {
        // ---- featT transpose + shortcut; 64 positions ----
        const int pos0 = b * 64;
        __shared__ float tF[64][66];
        __shared__ float scw_l[3][64];
        __shared__ float scb_l[4];
        {
            const int p = tid & 63, cg = tid >> 6;
            #pragma unroll
            for (int cc = 0; cc < 16; ++cc) {
                const int c = cg * 16 + cc;
                tF[c][p] = ldin(feat, c * NIN + pos0 + p, f32);
            }
        }
        if (tid < 192)
            scw_l[tid >> 6][tid & 63] = ldin(sc_pw_w, tid, f32) * ldin(sc_dw_w, tid & 63, f32);
        if (tid < 3) {
            float sb = ldin(sc_pw_b, tid, f32);
            for (int c = 0; c < 64; ++c)
                sb += ldin(sc_pw_w, tid * 64 + c, f32) * ldin(sc_dw_b, c, f32);
            scb_l[tid] = sb;
        }
        __syncthreads();
        #pragma unroll
        for (int it = 0; it < 2; ++it) {
            const int id = it * 256 + tid;          // 0..511
            const int p = id >> 3, c8 = id & 7;
            bf16 v[8];
            #pragma unroll
            for (int jj = 0; jj < 8; ++jj) v[jj] = f2b(tF[c8 * 8 + jj][p]);
            *(short8x*)&featT[(size_t)(pos0 + p) * 64 + c8 * 8] = *(short8x*)v;
        }
        if (tid < 192) {
            const int j = tid >> 6, p = tid & 63;
            float s = scb_l[j];
            for (int c = 0; c < 64; ++c) s += tF[c][p] * scw_l[j][c];
            F[F_SC + j * NIN + pos0 + p] = s;
        }
        return;
    }
    if (b < 214) {
        // ---- W1fP pack: g in [0,16384), one fragment per thread ----
        const int g = (b - 150) * 256 + tid;
        const int kc = g >> 10, nt = (g >> 6) & 15, wl = g & 63;
        const int n = nt * 16 + (wl & 15);
        const int K0 = kc * 32 + (wl >> 4) * 8;
        bf16 v[8];
        #pragma unroll
        for (int jj = 0; jj < 8; ++jj) {
            const int ch = 24 + K0 + jj;
            v[jj] = f2b(ldin(pw1_w, n * 539 + ch, f32) * ldin(dw1_w, ch, f32));
        }
        *(short8x*)&W1fP[(size_t)g * 8] = *(short8x*)v;
        return;
    }
    if (b < 246) {
        // ---- fc1P pack: g in [0,8192), one fragment per thread ----
        const int g = (b - 214) * 256 + tid;
        const int kc = g >> 10, nt = (g >> 6) & 15, wl = g & 63;
        const int n = nt * 16 + (wl & 15);
        const int K0 = kc * 32 + (wl >> 4) * 8;
        bf16 v[8];
        #pragma unroll
        for (int jj = 0; jj < 8; ++jj) v[jj] = f2b(ldin(fc1_w, n * 256 + K0 + jj, f32));
        *(short8x*)&fc1P[(size_t)g * 8] = *(short8x*)v;
        return;
    }
    if (b < 262) {
        // ---- B1 + ACO fold: channels n = (b-246)*16 + r ----
        const int r = tid >> 4, part = tid & 15;
        const int n = (b - 246) * 16 + r;
        float s = 0.f;
        for (int ch = part; ch < 539; ch += 16)
            s += ldin(pw1_w, n * 539 + ch, f32) * ldin(dw1_b, ch, f32);
        #pragma unroll
        for (int m = 1; m <= 8; m <<= 1) s += __shfl_xor(s, m, 64);
        if (part == 0) {
            float bacc = ldin(pw1_b, n, f32) + s;
            #pragma unroll
            for (int ch = 536; ch < 539; ++ch)
                bacc += 2.0f * ldin(pw1_w, n * 539 + ch, f32) * ldin(dw1_w, ch, f32);
            F[F_B1 + n] = bacc;
            float A[6] = {0.f, 0.f, 0.f, 0.f, 0.f, 0.f};
            #pragma unroll
            for (int k = 0; k < 8; ++k) {
                A[(k >> 2)]           += ldin(pw1_w, n*539 + 3*k + 0, f32) * ldin(dw1_w, 3*k + 0, f32);
                A[2 + ((k >> 1) & 1)] += ldin(pw1_w, n*539 + 3*k + 1, f32) * ldin(dw1_w, 3*k + 1, f32);
                A[4 + (k & 1)]        += ldin(pw1_w, n*539 + 3*k + 2, f32) * ldin(dw1_w, 3*k + 2, f32);
            }
            #pragma unroll
            for (int i = 0; i < 6; ++i) F[F_ACO + i * 256 + n] = A[i];
        }
        return;
    }
    // ---- block 262: flag + tables + small staging ----
    if (tid == 0) I[I_FLAG] = f32;
    F[F_FC1B + tid] = ldin(fc1_b, tid, f32);
    for (int r = tid; r < 768; r += 256) F[F_FC2W + r] = ldin(fc2_w, r, f32);
    if (tid < 3) F[F_FC2B + tid] = ldin(fc2_b, tid, f32);
    if (tid < TO) axis_tables(tid, TO, TI, F + F_DT, I + I_IT, I + I_LT0, I + I_LT1, F + F_FT);
    if (tid < HO) axis_tables(tid, HO, HI, F + F_DH, I + I_IH, I + I_LH0, I + I_LH1, F + F_FH);
    if (tid < WO) axis_tables(tid, WO, WI, F + F_DW, I + I_IW, I + I_LW0, I + I_LW1, F + F_FW);
}

// ---------------- kernel B: fully fused main (z-GEMM K=512 -> fc1 -> gelu -> fc2) ----------------
// no min-wave bound: let the allocator use what it needs (round-7 spill post-mortem)
__global__ __launch_bounds__(256)
void k_main(const bf16* __restrict__ featT, const bf16* __restrict__ fc1P,
            const bf16* __restrict__ W1fP, const float* __restrict__ F,
            const int* __restrict__ I, void* __restrict__ outv) {
    const int tid = threadIdx.x;
    const int pos0 = blockIdx.x * MPOS;
    const int f32 = I[I_FLAG];

    __shared__ __align__(16) short ubuf[MPOS * USTR];  // u[p][corner][c]; aliased as z[p][o] later
    __shared__ float redc[MPOS * 4 * 3];
    __shared__ int   sh_ipos[MPOS][8];
    __shared__ float sh_wk[MPOS][8];
    __shared__ float sh_dv[MPOS][6];
    __shared__ float sh_g[3][MPOS];

    // ---- stage 1: per-position scalars (threads 0..31) ----
    if (tid < MPOS) {
        const int p = tid;
        const int pos = pos0 + p;
        const int t = pos / (HO * WO);
        const int rem = pos - t * (HO * WO);
        const int h = rem / WO;
        const int w = rem - h * WO;
        const int   iTa[2] = { I[I_IT + t], I[I_IT + TO + t] };
        const float dTv[2] = { F[F_DT + t], F[F_DT + TO + t] };
        const int   iHa[2] = { I[I_IH + h], I[I_IH + HO + h] };
        const float dHv[2] = { F[F_DH + h], F[F_DH + HO + h] };
        const int   iWa[2] = { I[I_IW + w], I[I_IW + WO + w] };
        const float dWv[2] = { F[F_DW + w], F[F_DW + WO + w] };
        sh_dv[p][0] = dTv[0]; sh_dv[p][1] = dTv[1];
        sh_dv[p][2] = dHv[0]; sh_dv[p][3] = dHv[1];
        sh_dv[p][4] = dWv[0]; sh_dv[p][5] = dWv[1];
        const float aT[2] = { fabsf(dTv[0]), fabsf(dTv[1]) };
        const float aH[2] = { fabsf(dHv[0]), fabsf(dHv[1]) };
        const float aW[2] = { fabsf(dWv[0]), fabsf(dWv[1]) };
        const float tot = (aT[0] + aT[1]) * (aH[0] + aH[1]) * (aW[0] + aW[1]) + 8e-9f;
        #pragma unroll
        for (int k = 0; k < 8; ++k) {
            const int at = k >> 2, ah = (k >> 1) & 1, aw = k & 1;
            sh_wk[p][k] = (aT[1 - at] * aH[1 - ah] * aW[1 - aw] + 1e-9f) / tot;
            sh_ipos[p][k] = iTa[at] * (HI * WI) + iHa[ah] * WI + iWa[aw];
        }
        // trilinear shortcut g
        const int a0 = I[I_LT0 + t], a1 = I[I_LT1 + t];
        const int bh0 = I[I_LH0 + h], bh1 = I[I_LH1 + h];
        const int c0 = I[I_LW0 + w], c1 = I[I_LW1 + w];
        const float fT = F[F_FT + t], fH = F[F_FH + h], fW = F[F_FW + w];
        #pragma unroll
        for (int jj = 0; jj < 3; ++jj) {
            const float* Sj = F + F_SC + jj * NIN;
            const int i0 = a0 * (HI * WI), i1 = a1 * (HI * WI);
            const float v000 = Sj[i0 + bh0 * WI + c0], v001 = Sj[i0 + bh0 * WI + c1];
            const float v010 = Sj[i0 + bh1 * WI + c0], v011 = Sj[i0 + bh1 * WI + c1];
            const float v100 = Sj[i1 + bh0 * WI + c0], v101 = Sj[i1 + bh0 * WI + c1];
            const float v110 = Sj[i1 + bh1 * WI + c0], v111 = Sj[i1 + bh1 * WI + c1];
            const float u00 = v000 * (1.f - fT) + v100 * fT;
            const float u01 = v001 * (1.f - fT) + v101 * fT;
            const float u10 = v010 * (1.f - fT) + v110 * fT;
            const float u11 = v011 * (1.f - fT) + v111 * fT;
            const float q0 = u00 * (1.f - fH) + u10 * fH;
            const float q1 = u01 * (1.f - fH) + u11 * fH;
            sh_g[jj][p] = q0 * (1.f - fW) + q1 * fW;
        }
    }
    __syncthreads();

    // ---- stage 2: build u[p][k][c] = wk * featT[ipos[p][k]][c]  (bf16) ----
    {
        const int c8 = tid & 7;
        int pair = tid >> 3;                 // (p,k) pair index, +32 per iter
        #pragma unroll
        for (int it = 0; it < 8; ++it, pair += 32) {
            const int p = pair >> 3, k = pair & 7;
            const int row = sh_ipos[p][k];
            const float wk = sh_wk[p][k];
            const short8x fr = *(const short8x*)(featT + (size_t)row * 64 + c8 * 8);
            short v[8];
            #pragma unroll
            for (int jj = 0; jj < 8; ++jj)
                v[jj] = bbits(wk * bu2f((unsigned short)fr[jj]));
            *(short8x*)&ubuf[p * USTR + k * CSTR + c8 * 8] = *(short8x*)v;
        }
    }
    __syncthreads();

    // ---- stage 3: z-GEMM (M=32,N=256,K=512) + bias/ACO epilogue -> z bf16 in ubuf ----
    const int wl = tid & 63, w = tid >> 6;
    const int col = wl & 15, quad = wl >> 4;
    {
        f32x4 zacc[2][4] = { { {0,0,0,0},{0,0,0,0},{0,0,0,0},{0,0,0,0} },
                             { {0,0,0,0},{0,0,0,0},{0,0,0,0},{0,0,0,0} } };
        const short8x* bp = (const short8x*)W1fP;
        #pragma unroll 2
        for (int kc = 0; kc < 16; ++kc) {
            const int corner = kc >> 1;
            const int cin = (kc & 1) * 32 + quad * 8;
            const short8x a0 = *(const short8x*)&ubuf[col * USTR + corner * CSTR + cin];
            const short8x a1 = *(const short8x*)&ubuf[(col + 16) * USTR + corner * CSTR + cin];
            #pragma unroll
            for (int nt = 0; nt < 4; ++nt) {
                const short8x bb = bp[((size_t)kc * 16 + w * 4 + nt) * 64 + wl];
                zacc[0][nt] = __builtin_amdgcn_mfma_f32_16x16x32_bf16(a0, bb, zacc[0][nt], 0, 0, 0);
                zacc[1][nt] = __builtin_amdgcn_mfma_f32_16x16x32_bf16(a1, bb, zacc[1][nt], 0, 0, 0);
            }
        }
        __syncthreads();   // all u reads complete before aliasing ubuf as z
        // epilogue: z = zacc + b1 + Acoef·dv; D layout m=quad*4+r (+16 mt), n=w*64+nt*16+col
        #pragma unroll
        for (int nt = 0; nt < 4; ++nt) {
            const int n = w * 64 + nt * 16 + col;
            const float b1 = F[F_B1 + n];
            float Ac[6];
            #pragma unroll
            for (int i = 0; i < 6; ++i) Ac[i] = F[F_ACO + i * 256 + n];
            #pragma unroll
            for (int mt = 0; mt < 2; ++mt)
                #pragma unroll
                for (int r = 0; r < 4; ++r) {
                    const int p = mt * 16 + quad * 4 + r;
                    float x = zacc[mt][nt][r] + b1;
                    #pragma unroll
                    for (int i = 0; i < 6; ++i) x += Ac[i] * sh_dv[p][i];
                    ubuf[p * ZPAD + n] = bbits(x);
                }
        }
    }
    __syncthreads();

    // ---- stage 4: fc1 via MFMA + gelu + fc2 partials in-register ----
    {
        f32x4 acc0[4] = { {0,0,0,0}, {0,0,0,0}, {0,0,0,0}, {0,0,0,0} };
        f32x4 acc1[4] = { {0,0,0,0}, {0,0,0,0}, {0,0,0,0}, {0,0,0,0} };
        const short8x* bp = (const short8x*)fc1P;
        #pragma unroll 2
        for (int kc = 0; kc < 8; ++kc) {
            const short8x a0 = *(const short8x*)&ubuf[col * ZPAD + kc * 32 + quad * 8];
            const short8x a1 = *(const short8x*)&ubuf[(col + 16) * ZPAD + kc * 32 + quad * 8];
            #pragma unroll
            for (int nt = 0; nt < 4; ++nt) {
                const short8x b = bp[((size_t)kc * 16 + w * 4 + nt) * 64 + wl];
                acc0[nt] = __builtin_amdgcn_mfma_f32_16x16x32_bf16(a0, b, acc0[nt], 0, 0, 0);
                acc1[nt] = __builtin_amdgcn_mfma_f32_16x16x32_bf16(a1, b, acc1[nt], 0, 0, 0);
            }
        }
        float part[2][3][4];
        #pragma unroll
        for (int mt = 0; mt < 2; ++mt)
            #pragma unroll
            for (int jj = 0; jj < 3; ++jj)
                #pragma unroll
                for (int r = 0; r < 4; ++r) part[mt][jj][r] = 0.f;
        #pragma unroll
        for (int nt = 0; nt < 4; ++nt) {
            const int j = w * 64 + nt * 16 + col;
            const float fb = F[F_FC1B + j];
            const float w0 = F[F_FC2W + j];
            const float w1 = F[F_FC2W + 256 + j];
            const float w2 = F[F_FC2W + 512 + j];
            #pragma unroll
            for (int r = 0; r < 4; ++r) {
                float hh = gelu_f(acc0[nt][r] + fb);
                part[0][0][r] += w0 * hh; part[0][1][r] += w1 * hh; part[0][2][r] += w2 * hh;
                hh = gelu_f(acc1[nt][r] + fb);
                part[1][0][r] += w0 * hh; part[1][1][r] += w1 * hh; part[1][2][r] += w2 * hh;
            }
        }
        // butterfly-reduce over the 16 col-lanes
        #pragma unroll
        for (int m = 1; m <= 8; m <<= 1)
            #pragma unroll
            for (int mt = 0; mt < 2; ++mt)
                #pragma unroll
                for (int jj = 0; jj < 3; ++jj)
                    #pragma unroll
                    for (int r = 0; r < 4; ++r)
                        part[mt][jj][r] += __shfl_xor(part[mt][jj][r], m, 64);
        if (col == 0) {
            #pragma unroll
            for (int mt = 0; mt < 2; ++mt)
                #pragma unroll
                for (int jj = 0; jj < 3; ++jj)
                    #pragma unroll
                    for (int r = 0; r < 4; ++r) {
                        const int p = mt * 16 + quad * 4 + r;
                        redc[(p * 4 + w) * 3 + jj] = part[mt][jj][r];
                    }
        }
    }
    __syncthreads();

    // ---- stage 5: combine 4 wave-partials + shortcut + store ----
    if (tid < 96) {
        const int p = tid / 3, jj = tid - 3 * p;
        float a = F[F_FC2B + jj] + sh_g[jj][p];
        #pragma unroll
        for (int w2 = 0; w2 < 4; ++w2) a += redc[(p * 4 + w2) * 3 + jj];
        const int oidx = jj * NOUT + pos0 + p;
        if (f32) ((float*)outv)[oidx] = a;
        else     ((bf16*)outv)[oidx] = f2b(a);
    }
}

extern "C" void kernel_launch(void* const* d_in, const int* in_sizes, int n_in,
                              void* d_out, int out_size, void* d_ws, size_t ws_size,
                              hipStream_t stream) {
    const void* feat    = d_in[0];
    const void* dw1_w   = d_in[1];
    const void* dw1_b   = d_in[2];
    const void* pw1_w   = d_in[3];
    const void* pw1_b   = d_in[4];
    const void* fc1_w   = d_in[5];
    const void* fc1_b   = d_in[6];
    const void* fc2_w   = d_in[7];
    const void* fc2_b   = d_in[8];
    const void* sc_dw_w = d_in[9];
    const void* sc_dw_b = d_in[10];
    const void* sc_pw_w = d_in[11];
    const void* sc_pw_b = d_in[12];

    const size_t FEATT_BYTES = (size_t)NIN * 64 * 2;      // 1,228,800
    const size_t FC1P_BYTES  = (size_t)256 * 256 * 2;     // 131,072
    const size_t W1FP_BYTES  = (size_t)512 * 256 * 2;     // 262,144
    bf16*  featT = (bf16*)d_ws;
    bf16*  fc1P  = (bf16*)((char*)d_ws + FEATT_BYTES);
    bf16*  W1fP  = (bf16*)((char*)d_ws + FEATT_BYTES + FC1P_BYTES);
    float* F     = (float*)((char*)d_ws + FEATT_BYTES + FC1P_BYTES + W1FP_BYTES);
    int*   I     = (int*)(F + F_END);
    // total ws need ~1.8 MB

    k_setup<<<263, 256, 0, stream>>>(feat, dw1_w, dw1_b, pw1_w, pw1_b, fc1_w, fc1_b,
                                     fc2_w, fc2_b, sc_dw_w, sc_dw_b, sc_pw_w, sc_pw_b,
                                     featT, fc1P, W1fP, F, I);
    k_main<<<NOUT / MPOS, 256, 0, stream>>>(featT, fc1P, W1fP, F, I, (void*)d_out);
}